// Round 5
// baseline (272.085 us; speedup 1.0000x reference)
//
#include <hip/hip_runtime.h>
#include <stdint.h>

#define EMB 768
#define NBATCH 8
#define SEQ 2048
#define M_TOT (NBATCH*SEQ)   // 16384

using bf16x8 = __attribute__((ext_vector_type(8))) short;
using f32x4  = __attribute__((ext_vector_type(4))) float;

__device__ __forceinline__ short f2bf(float f) {
  __bf16 h = (__bf16)f;
  return __builtin_bit_cast(short, h);
}
__device__ __forceinline__ short f2h(float f) {
  _Float16 h = (_Float16)f;
  return __builtin_bit_cast(short, h);
}
__device__ __forceinline__ float h2f(short s) {
  return (float)__builtin_bit_cast(_Float16, s);
}
__device__ __forceinline__ f32x4 MFMA(bf16x8 a, bf16x8 b, f32x4 c) {
  return __builtin_amdgcn_mfma_f32_16x16x32_bf16(a, b, c, 0, 0, 0);
}
#define GLOAD_LDS16(g, l) __builtin_amdgcn_global_load_lds( \
    (const __attribute__((address_space(1))) unsigned int*)(g), \
    (__attribute__((address_space(3))) unsigned int*)(l), 16, 0, 0)

// ---------------------------------------------------------------------------
// cvt_all: x, Wq|Wk|Wv fp32 -> bf16 (Wb rows 0..767=Wq, 768..1535=Wk, rest Wv)
// ---------------------------------------------------------------------------
__global__ __launch_bounds__(256) void cvt_all(
    const float* __restrict__ x, const float* __restrict__ Wq,
    const float* __restrict__ Wk, const float* __restrict__ Wv,
    short* __restrict__ xb, short* __restrict__ Wb)
{
  const size_t NXU = (size_t)M_TOT * EMB / 8;
  const size_t NWU = (size_t)EMB * EMB / 8;
  const size_t total = NXU + 3 * NWU;
  for (size_t u = (size_t)blockIdx.x * 256 + threadIdx.x; u < total;
       u += (size_t)gridDim.x * 256) {
    const float* src; short* dst; size_t off;
    if (u < NXU)            { src = x;  dst = xb;                     off = u; }
    else if (u < NXU+NWU)   { src = Wq; dst = Wb;                     off = u - NXU; }
    else if (u < NXU+2*NWU) { src = Wk; dst = Wb + (size_t)EMB*EMB;   off = u - NXU - NWU; }
    else                    { src = Wv; dst = Wb + (size_t)2*EMB*EMB; off = u - NXU - 2*NWU; }
    float4 a = reinterpret_cast<const float4*>(src)[off*2];
    float4 c = reinterpret_cast<const float4*>(src)[off*2+1];
    bf16x8 o;
    o[0]=f2bf(a.x); o[1]=f2bf(a.y); o[2]=f2bf(a.z); o[3]=f2bf(a.w);
    o[4]=f2bf(c.x); o[5]=f2bf(c.y); o[6]=f2bf(c.z); o[7]=f2bf(c.w);
    reinterpret_cast<bf16x8*>(dst)[off] = o;
  }
}

// ---------------------------------------------------------------------------
// 8-phase 256x256 GEMM machinery (T3+T4+T5). BK=64, 8 waves (2m x 4n),
// 512 thr, 128KB LDS dbuf. Per phase: quadrant (mh,nh) = 16 MFMA, 12
// ds_read_b128, stage 1 half-tile (2 gload_lds), vmcnt(4) counted wait,
// raw s_barrier (asm, memory clobber).
// Stage order per tile: A0,B0,B1,A1.
// Main-loop ledger (FIFO, per wave): steady-state outstanding = 4; every
// half-tile is retired by an EARLIER phase's vmcnt(4) + barrier before its
// first ds_read (A.h0 at prev PHASE(1,0), B.h0 at prev PHASE(1,1),
// B.h1 at PHASE(0,0), A.h1 at PHASE(0,1)).
// EPILOGUE (R5 fix): ds_reads precede each phase's vmcnt, so counted waits
// cannot protect the LAST tile's halves (queue at entry = [B.h1, A.h1]) --
// R4 raced here. Drain vmcnt(0)+barrier ONCE before the final 4 quadrants.
// Swizzle: granule g ^= (row&7), pre-swizzled global source, linear LDS.
// ---------------------------------------------------------------------------
#define STAGE_HALF(ldsb, src, ld, k0, h)                                      \
  { _Pragma("unroll") for (int i_ = 0; i_ < 2; ++i_) {                        \
      int slot_ = i_*512 + t;                                                 \
      int row_ = (h)*128 + (slot_ >> 3), g_ = slot_ & 7;                      \
      GLOAD_LDS16((src) + (size_t)row_*(ld) + (k0) + ((g_ ^ (row_ & 7)) << 3),\
                  (ldsb) + (h)*16384 + (size_t)(i_*512 + w*64)*16); } }

#define PHASE(mh, nh, W, ...)                                                 \
  {                                                                           \
    bf16x8 af_[2][4], bfr_[2][2];                                             \
    _Pragma("unroll") for (int ks_ = 0; ks_ < 2; ++ks_) {                     \
      _Pragma("unroll") for (int mi_ = 0; mi_ < 4; ++mi_) {                   \
        int r_ = (mh)*128 + wm*64 + mi_*16 + l15;                             \
        af_[ks_][mi_] = *reinterpret_cast<const bf16x8*>(                     \
            Ar + r_*64 + (((ks_*4 + l4) ^ (r_ & 7)) << 3));                   \
      }                                                                       \
      _Pragma("unroll") for (int ni_ = 0; ni_ < 2; ++ni_) {                   \
        int r_ = (nh)*128 + wn*32 + ni_*16 + l15;                             \
        bfr_[ks_][ni_] = *reinterpret_cast<const bf16x8*>(                    \
            Br + r_*64 + (((ks_*4 + l4) ^ (r_ & 7)) << 3));                   \
      }                                                                       \
    }                                                                         \
    __VA_ARGS__                                                               \
    asm volatile("s_waitcnt vmcnt(" #W ")" ::: "memory");                     \
    asm volatile("s_barrier" ::: "memory");                                   \
    __builtin_amdgcn_s_setprio(1);                                            \
    _Pragma("unroll") for (int ks_ = 0; ks_ < 2; ++ks_)                       \
      _Pragma("unroll") for (int mi_ = 0; mi_ < 4; ++mi_)                     \
        _Pragma("unroll") for (int ni_ = 0; ni_ < 2; ++ni_)                   \
          acc[mh][nh][mi_][ni_] =                                             \
              MFMA(af_[ks_][mi_], bfr_[ks_][ni_], acc[mh][nh][mi_][ni_]);     \
    __builtin_amdgcn_s_setprio(0);                                            \
    asm volatile("s_barrier" ::: "memory");                                   \
  }

#define GEMM_PRO_BODY(asrc, bsrc, lda, ldb, NT)                               \
  short* const A0p = (short*)smem;                                            \
  short* const B0p = (short*)(smem + 32768);                                  \
  short* const A1p = (short*)(smem + 65536);                                  \
  short* const B1p = (short*)(smem + 98304);                                  \
  f32x4 acc[2][2][4][2] = {};                                                 \
  STAGE_HALF((char*)A0p, asrc, lda, 0, 0);                                    \
  STAGE_HALF((char*)B0p, bsrc, ldb, 0, 0);                                    \
  STAGE_HALF((char*)B0p, bsrc, ldb, 0, 1);                                    \
  STAGE_HALF((char*)A0p, asrc, lda, 0, 1);                                    \
  asm volatile("s_waitcnt vmcnt(4)" ::: "memory");                            \
  asm volatile("s_barrier" ::: "memory");                                     \
  for (int T = 0; T < (NT) - 1; ++T) {                                        \
    short* Ar = (T & 1) ? A1p : A0p;                                          \
    short* Br = (T & 1) ? B1p : B0p;                                          \
    char* Aw = (char*)((T & 1) ? A0p : A1p);                                  \
    char* Bw = (char*)((T & 1) ? B0p : B1p);                                  \
    const int nk = (T + 1) * 64;                                              \
    PHASE(0,0, 4, STAGE_HALF(Aw, asrc, lda, nk, 0))                           \
    PHASE(0,1, 4, STAGE_HALF(Bw, bsrc, ldb, nk, 0))                           \
    PHASE(1,0, 4, STAGE_HALF(Bw, bsrc, ldb, nk, 1))                           \
    PHASE(1,1, 4, STAGE_HALF(Aw, asrc, lda, nk, 1))                           \
  }                                                                           \
  {                                                                           \
    short* Ar = (((NT)-1) & 1) ? A1p : A0p;                                   \
    short* Br = (((NT)-1) & 1) ? B1p : B0p;                                   \
    asm volatile("s_waitcnt vmcnt(0)" ::: "memory");  /* R5: drain-first */   \
    asm volatile("s_barrier" ::: "memory");                                   \
    PHASE(0,0, 0)                                                             \
    PHASE(0,1, 0)                                                             \
    PHASE(1,0, 0)                                                             \
    PHASE(1,1, 0)                                                             \
  }

// ---------------------------------------------------------------------------
// qkv: C[m,f] = sum_e xb[m,e]*Wb[f,e]. Grid 576 = 64 bm x 9 bn.
// Q/K row-major; V transposed (Vt[b][d][s]).
// ---------------------------------------------------------------------------
__global__ __launch_bounds__(512, 2) void qkv_gemm(
    const short* __restrict__ xb, const short* __restrict__ Wb,
    short* __restrict__ Qb, short* __restrict__ Kb, short* __restrict__ Vt)
{
  extern __shared__ char smem[];
  const int t = threadIdx.x, lane = t & 63, w = t >> 6;
  const int wm = w >> 2, wn = w & 3, l15 = lane & 15, l4 = lane >> 4;

  const int bid = blockIdx.x;
  const int nb = (bid & 7) * 72 + (bid >> 3);      // 576 % 8 == 0, bijective
  const int bm = nb / 9, bn = nb % 9;

  const short* asrc = xb + (size_t)bm * 256 * EMB;
  const short* bsrc = Wb + (size_t)bn * 256 * EMB;

  GEMM_PRO_BODY(asrc, bsrc, EMB, EMB, 12)

#pragma unroll
  for (int mh = 0; mh < 2; ++mh)
#pragma unroll
  for (int nh = 0; nh < 2; ++nh)
#pragma unroll
  for (int mi = 0; mi < 4; ++mi)
#pragma unroll
  for (int ni = 0; ni < 2; ++ni) {
    int f  = bn*256 + nh*128 + wn*32 + ni*16 + l15;
    int m0 = bm*256 + mh*128 + wm*64 + mi*16 + l4*4;
    f32x4 v = acc[mh][nh][mi][ni];
    if (f < 1536) {
      short* dst = (f < 768) ? (Qb + f) : (Kb + (f - 768));
#pragma unroll
      for (int j = 0; j < 4; ++j)
        dst[(size_t)(m0 + j) * EMB] = f2bf(v[j]);
    } else {
      int f2 = f - 1536, bb2 = m0 >> 11, s = m0 & 2047;
      short4 pk = make_short4(f2bf(v[0]), f2bf(v[1]), f2bf(v[2]), f2bf(v[3]));
      *reinterpret_cast<short4*>(&Vt[((size_t)bb2 * EMB + f2) * SEQ + s]) = pk;
    }
  }
}

// ---------------------------------------------------------------------------
// energy: S[b,q,k] = (Q.K)*log2e/sqrt(768), fp16 (mask applied in softmax).
// Grid 512 = 8 b x 64 (4x4 supertiles of 2x2 of 8qt x 8kt). Batch == XCD.
// ---------------------------------------------------------------------------
__global__ __launch_bounds__(512, 2) void energy(
    const short* __restrict__ Qb, const short* __restrict__ Kb,
    short* __restrict__ S)
{
  extern __shared__ char smem[];
  const int t = threadIdx.x, lane = t & 63, w = t >> 6;
  const int wm = w >> 2, wn = w & 3, l15 = lane & 15, l4 = lane >> 4;

  const int bid = blockIdx.x;
  const int nb = (bid & 7) * 64 + (bid >> 3);      // 512 % 8 == 0
  const int b = nb >> 6;                           // batch per XCD
  const int idx = nb & 63;
  const int sup = idx >> 2, sub = idx & 3;         // 2x2 supertiles
  const int qt = (sup >> 2) * 2 + (sub >> 1);
  const int kt = (sup & 3) * 2 + (sub & 1);

  const short* asrc = Qb + ((size_t)b*SEQ + qt*256) * EMB;
  const short* bsrc = Kb + ((size_t)b*SEQ + kt*256) * EMB;

  GEMM_PRO_BODY(asrc, bsrc, EMB, EMB, 12)

  const float SCL = 1.4426950408889634f / 27.712812921102035f;  // log2e/sqrt(768)
  short* srow = S + (size_t)b * SEQ * SEQ;
#pragma unroll
  for (int mh = 0; mh < 2; ++mh)
#pragma unroll
  for (int nh = 0; nh < 2; ++nh)
#pragma unroll
  for (int mi = 0; mi < 4; ++mi)
#pragma unroll
  for (int ni = 0; ni < 2; ++ni)
#pragma unroll
  for (int j = 0; j < 4; ++j) {
    int q = qt*256 + mh*128 + wm*64 + mi*16 + l4*4 + j;
    int k = kt*256 + nh*128 + wn*32 + ni*16 + l15;
    srow[(size_t)q*SEQ + k] = f2h(acc[mh][nh][mi][ni][j] * SCL);
  }
}

// ---------------------------------------------------------------------------
// softmax_rows: one wave per row; fp16 scores + int4 mask stream; bf16 P
// in place; invl = 1/sum. (unchanged, R3)
// ---------------------------------------------------------------------------
__global__ __launch_bounds__(256, 8) void softmax_rows(
    short* __restrict__ S, const int* __restrict__ mask,
    float* __restrict__ invl)
{
  const int w = threadIdx.x >> 6, lane = threadIdx.x & 63;
  const int r = blockIdx.x * 4 + w;
  short* row = S + (size_t)r * SEQ;
  const int4* mrow = reinterpret_cast<const int4*>(mask + (size_t)r * SEQ);

  float f[32];
#pragma unroll
  for (int c = 0; c < 4; ++c) {
    bf16x8 v = *reinterpret_cast<const bf16x8*>(&row[c*512 + lane*8]);
    int4 m0 = mrow[(c*512 + lane*8) >> 2];
    int4 m1 = mrow[((c*512 + lane*8) >> 2) + 1];
    f[c*8+0] = m0.x ? h2f(v[0]) : -30000.0f;
    f[c*8+1] = m0.y ? h2f(v[1]) : -30000.0f;
    f[c*8+2] = m0.z ? h2f(v[2]) : -30000.0f;
    f[c*8+3] = m0.w ? h2f(v[3]) : -30000.0f;
    f[c*8+4] = m1.x ? h2f(v[4]) : -30000.0f;
    f[c*8+5] = m1.y ? h2f(v[5]) : -30000.0f;
    f[c*8+6] = m1.z ? h2f(v[6]) : -30000.0f;
    f[c*8+7] = m1.w ? h2f(v[7]) : -30000.0f;
  }
  float m = -3.0e38f;
#pragma unroll
  for (int i = 0; i < 32; ++i) m = fmaxf(m, f[i]);
#pragma unroll
  for (int off = 32; off >= 1; off >>= 1) m = fmaxf(m, __shfl_xor(m, off));
  float sum = 0.f;
#pragma unroll
  for (int i = 0; i < 32; ++i) {
    f[i] = __builtin_amdgcn_exp2f(f[i] - m);
    sum += f[i];
  }
#pragma unroll
  for (int off = 32; off >= 1; off >>= 1) sum += __shfl_xor(sum, off);

#pragma unroll
  for (int c = 0; c < 4; ++c) {
    bf16x8 o;
#pragma unroll
    for (int j = 0; j < 8; ++j) o[j] = f2bf(f[c*8 + j]);
    *reinterpret_cast<bf16x8*>(&row[c*512 + lane*8]) = o;
  }
  if (lane == 0) invl[r] = 1.0f / sum;
}

// ---------------------------------------------------------------------------
// pv: out[b,q,d] = invl[b,q] * sum_k P[b,q,k]*Vt[b,d,k]. Grid 192 =
// 8 b x 8 qt x 3 dt (batch per XCD). K-tiles 32.
// ---------------------------------------------------------------------------
__global__ __launch_bounds__(512, 2) void pv(
    const short* __restrict__ P, const short* __restrict__ Vt,
    const float* __restrict__ invl, float* __restrict__ out)
{
  extern __shared__ char smem[];
  const int t = threadIdx.x, lane = t & 63, w = t >> 6;
  const int wm = w >> 2, wn = w & 3, l15 = lane & 15, l4 = lane >> 4;

  const int bid = blockIdx.x;
  const int nb = (bid & 7) * 24 + (bid >> 3);      // 192 % 8 == 0
  const int b = nb / 24;
  const int idx = nb % 24;
  const int qt = idx / 3, dt = idx % 3;

  const short* asrc = P  + ((size_t)b*SEQ + qt*256) * SEQ;
  const short* bsrc = Vt + ((size_t)b*EMB + dt*256) * SEQ;

  GEMM_PRO_BODY(asrc, bsrc, SEQ, SEQ, 32)

#pragma unroll
  for (int mh = 0; mh < 2; ++mh)
#pragma unroll
  for (int nh = 0; nh < 2; ++nh)
#pragma unroll
  for (int mi = 0; mi < 4; ++mi)
#pragma unroll
  for (int j = 0; j < 4; ++j) {
    int q = qt*256 + mh*128 + wm*64 + mi*16 + l4*4 + j;
    float il = invl[b*SEQ + q];
    float* orow = out + ((size_t)b*SEQ + q) * EMB;
#pragma unroll
    for (int ni = 0; ni < 2; ++ni) {
      int d = dt*256 + nh*128 + wn*32 + ni*16 + l15;
      orow[d] = acc[mh][nh][mi][ni][j] * il;
    }
  }
}

// ---------------------------------------------------------------------------
extern "C" void kernel_launch(void* const* d_in, const int* in_sizes, int n_in,
                              void* d_out, int out_size, void* d_ws, size_t ws_size,
                              hipStream_t stream)
{
  (void)in_sizes; (void)n_in; (void)out_size; (void)ws_size;
  const float* x  = (const float*)d_in[0];
  const float* Wv = (const float*)d_in[1];
  const float* Wk = (const float*)d_in[2];
  const float* Wq = (const float*)d_in[3];
  const int* mask = (const int*)d_in[4];
  float* out = (float*)d_out;

  // ws: Qb | Kb | Vt (bf16, 24MiB each) | S (fp16->bf16 in place, 64MiB) | invl
  // xb and Wb alias the S region (dead before energy writes S).
  short* Qb = (short*)d_ws;
  short* Kb = Qb + (size_t)M_TOT * EMB;
  short* Vt = Kb + (size_t)M_TOT * EMB;
  short* S  = Vt + (size_t)M_TOT * EMB;
  float* invl = (float*)(S + (size_t)NBATCH * SEQ * SEQ);
  short* xb = S;
  short* Wb = S + (size_t)M_TOT * EMB;

  cvt_all<<<dim3(2048), dim3(256), 0, stream>>>(x, Wq, Wk, Wv, xb, Wb);
  qkv_gemm<<<dim3(576), dim3(512), 131072, stream>>>(xb, Wb, Qb, Kb, Vt);
  energy<<<dim3(512), dim3(512), 131072, stream>>>(Qb, Kb, S);
  softmax_rows<<<dim3(4096), dim3(256), 0, stream>>>(S, mask, invl);
  pv<<<dim3(192), dim3(512), 131072, stream>>>(S, Vt, invl, out);
}

// Round 6
// 252.215 us; speedup vs baseline: 1.0788x; 1.0788x over previous
//
#include <hip/hip_runtime.h>
#include <stdint.h>

#define EMB 768
#define NBATCH 8
#define SEQ 2048
#define M_TOT (NBATCH*SEQ)   // 16384

using bf16x8 = __attribute__((ext_vector_type(8))) short;
using f32x4  = __attribute__((ext_vector_type(4))) float;

__device__ __forceinline__ short f2bf(float f) {
  __bf16 h = (__bf16)f;
  return __builtin_bit_cast(short, h);
}
__device__ __forceinline__ short f2h(float f) {
  _Float16 h = (_Float16)f;
  return __builtin_bit_cast(short, h);
}
__device__ __forceinline__ float h2f(short s) {
  return (float)__builtin_bit_cast(_Float16, s);
}
__device__ __forceinline__ f32x4 MFMA(bf16x8 a, bf16x8 b, f32x4 c) {
  return __builtin_amdgcn_mfma_f32_16x16x32_bf16(a, b, c, 0, 0, 0);
}
#define GLOAD_LDS16(g, l) __builtin_amdgcn_global_load_lds( \
    (const __attribute__((address_space(1))) unsigned int*)(g), \
    (__attribute__((address_space(3))) unsigned int*)(l), 16, 0, 0)

// ---------------------------------------------------------------------------
// cvt_all: x, Wq|Wk|Wv fp32 -> bf16 (Wb rows 0..767=Wq, 768..1535=Wk, rest Wv)
// ---------------------------------------------------------------------------
__global__ __launch_bounds__(256) void cvt_all(
    const float* __restrict__ x, const float* __restrict__ Wq,
    const float* __restrict__ Wk, const float* __restrict__ Wv,
    short* __restrict__ xb, short* __restrict__ Wb)
{
  const size_t NXU = (size_t)M_TOT * EMB / 8;
  const size_t NWU = (size_t)EMB * EMB / 8;
  const size_t total = NXU + 3 * NWU;
  for (size_t u = (size_t)blockIdx.x * 256 + threadIdx.x; u < total;
       u += (size_t)gridDim.x * 256) {
    const float* src; short* dst; size_t off;
    if (u < NXU)            { src = x;  dst = xb;                     off = u; }
    else if (u < NXU+NWU)   { src = Wq; dst = Wb;                     off = u - NXU; }
    else if (u < NXU+2*NWU) { src = Wk; dst = Wb + (size_t)EMB*EMB;   off = u - NXU - NWU; }
    else                    { src = Wv; dst = Wb + (size_t)2*EMB*EMB; off = u - NXU - 2*NWU; }
    float4 a = reinterpret_cast<const float4*>(src)[off*2];
    float4 c = reinterpret_cast<const float4*>(src)[off*2+1];
    bf16x8 o;
    o[0]=f2bf(a.x); o[1]=f2bf(a.y); o[2]=f2bf(a.z); o[3]=f2bf(a.w);
    o[4]=f2bf(c.x); o[5]=f2bf(c.y); o[6]=f2bf(c.z); o[7]=f2bf(c.w);
    reinterpret_cast<bf16x8*>(dst)[off] = o;
  }
}

// ---------------------------------------------------------------------------
// 8-phase 256x256 GEMM (T3+T4+T5), R6: fragment caching across quadrant
// phases. BK=64, 8 waves (2m x 4n), 512 thr, 128KB LDS dbuf.
// R5 post-mortem: quadrant phases re-read A/B halves -> 48 ds_read_b128 per
// K-tile per wave, 2x m201's 24 -> LDS-read-bound (MfmaUtil 23%). R6 caches
// fragments in registers: reads per phase = 12/4/8/0 (A.h0+B.h0 / B.h1 /
// A.h1 / none) = 24/K-tile, minimal.
// Sync structure UNCHANGED from verified R5: stage order A0,B0,B1,A1;
// vmcnt(4) per phase (main loop); drain-first vmcnt(0) epilogue.
// Ledger: steady-state outstanding=4; each half retired by an earlier
// phase's vmcnt(4)+barrier before its first ds_read.
// ---------------------------------------------------------------------------
#define STAGE_HALF(ldsb, src, ld, k0, h)                                      \
  { _Pragma("unroll") for (int i_ = 0; i_ < 2; ++i_) {                        \
      int slot_ = i_*512 + t;                                                 \
      int row_ = (h)*128 + (slot_ >> 3), g_ = slot_ & 7;                      \
      GLOAD_LDS16((src) + (size_t)row_*(ld) + (k0) + ((g_ ^ (row_ & 7)) << 3),\
                  (ldsb) + (h)*16384 + (size_t)(i_*512 + w*64)*16); } }

#define READ_A(mh)                                                            \
  _Pragma("unroll") for (int ks_ = 0; ks_ < 2; ++ks_)                         \
    _Pragma("unroll") for (int mi_ = 0; mi_ < 4; ++mi_) {                     \
      int r_ = (mh)*128 + wm*64 + mi_*16 + l15;                               \
      a_c[ks_][mi_] = *reinterpret_cast<const bf16x8*>(                       \
          Ar + r_*64 + (((ks_*4 + l4) ^ (r_ & 7)) << 3));                     \
    }

#define READ_B(nh)                                                            \
  _Pragma("unroll") for (int ks_ = 0; ks_ < 2; ++ks_)                         \
    _Pragma("unroll") for (int ni_ = 0; ni_ < 2; ++ni_) {                     \
      int r_ = (nh)*128 + wn*32 + ni_*16 + l15;                               \
      b_c[nh][ks_][ni_] = *reinterpret_cast<const bf16x8*>(                   \
          Br + r_*64 + (((ks_*4 + l4) ^ (r_ & 7)) << 3));                     \
    }

#define PHASE(mh, nh, W, RD, ...)                                             \
  {                                                                           \
    RD                                                                        \
    __VA_ARGS__                                                               \
    asm volatile("s_waitcnt vmcnt(" #W ")" ::: "memory");                     \
    asm volatile("s_barrier" ::: "memory");                                   \
    __builtin_amdgcn_s_setprio(1);                                            \
    _Pragma("unroll") for (int ks_ = 0; ks_ < 2; ++ks_)                       \
      _Pragma("unroll") for (int mi_ = 0; mi_ < 4; ++mi_)                     \
        _Pragma("unroll") for (int ni_ = 0; ni_ < 2; ++ni_)                   \
          acc[mh][nh][mi_][ni_] =                                             \
              MFMA(a_c[ks_][mi_], b_c[nh][ks_][ni_], acc[mh][nh][mi_][ni_]);  \
    __builtin_amdgcn_s_setprio(0);                                            \
    asm volatile("s_barrier" ::: "memory");                                   \
  }

#define GEMM_PRO_BODY(asrc, bsrc, lda, ldb, NT)                               \
  short* const A0p = (short*)smem;                                            \
  short* const B0p = (short*)(smem + 32768);                                  \
  short* const A1p = (short*)(smem + 65536);                                  \
  short* const B1p = (short*)(smem + 98304);                                  \
  f32x4 acc[2][2][4][2] = {};                                                 \
  bf16x8 a_c[2][4], b_c[2][2][2];                                             \
  STAGE_HALF((char*)A0p, asrc, lda, 0, 0);                                    \
  STAGE_HALF((char*)B0p, bsrc, ldb, 0, 0);                                    \
  STAGE_HALF((char*)B0p, bsrc, ldb, 0, 1);                                    \
  STAGE_HALF((char*)A0p, asrc, lda, 0, 1);                                    \
  asm volatile("s_waitcnt vmcnt(4)" ::: "memory");                            \
  asm volatile("s_barrier" ::: "memory");                                     \
  for (int T = 0; T < (NT) - 1; ++T) {                                        \
    short* Ar = (T & 1) ? A1p : A0p;                                          \
    short* Br = (T & 1) ? B1p : B0p;                                          \
    char* Aw = (char*)((T & 1) ? A0p : A1p);                                  \
    char* Bw = (char*)((T & 1) ? B0p : B1p);                                  \
    const int nk = (T + 1) * 64;                                              \
    PHASE(0,0, 4, READ_A(0) READ_B(0), STAGE_HALF(Aw, asrc, lda, nk, 0))      \
    PHASE(0,1, 4, READ_B(1),           STAGE_HALF(Bw, bsrc, ldb, nk, 0))      \
    PHASE(1,0, 4, READ_A(1),           STAGE_HALF(Bw, bsrc, ldb, nk, 1))      \
    PHASE(1,1, 4, ,                    STAGE_HALF(Aw, asrc, lda, nk, 1))      \
  }                                                                           \
  {                                                                           \
    short* Ar = (((NT)-1) & 1) ? A1p : A0p;                                   \
    short* Br = (((NT)-1) & 1) ? B1p : B0p;                                   \
    asm volatile("s_waitcnt vmcnt(0)" ::: "memory");  /* drain-first */       \
    asm volatile("s_barrier" ::: "memory");                                   \
    PHASE(0,0, 0, READ_A(0) READ_B(0), )                                      \
    PHASE(0,1, 0, READ_B(1), )                                                \
    PHASE(1,0, 0, READ_A(1), )                                                \
    PHASE(1,1, 0, , )                                                         \
  }

// ---------------------------------------------------------------------------
// qkv: C[m,f] = sum_e xb[m,e]*Wb[f,e]. Grid 576 = 64 bm x 9 bn.
// Q/K row-major; V transposed (Vt[b][d][s]).
// ---------------------------------------------------------------------------
__global__ __launch_bounds__(512, 2) void qkv_gemm(
    const short* __restrict__ xb, const short* __restrict__ Wb,
    short* __restrict__ Qb, short* __restrict__ Kb, short* __restrict__ Vt)
{
  extern __shared__ char smem[];
  const int t = threadIdx.x, lane = t & 63, w = t >> 6;
  const int wm = w >> 2, wn = w & 3, l15 = lane & 15, l4 = lane >> 4;

  const int bid = blockIdx.x;
  const int nb = (bid & 7) * 72 + (bid >> 3);      // 576 % 8 == 0, bijective
  const int bm = nb / 9, bn = nb % 9;

  const short* asrc = xb + (size_t)bm * 256 * EMB;
  const short* bsrc = Wb + (size_t)bn * 256 * EMB;

  GEMM_PRO_BODY(asrc, bsrc, EMB, EMB, 12)

#pragma unroll
  for (int mh = 0; mh < 2; ++mh)
#pragma unroll
  for (int nh = 0; nh < 2; ++nh)
#pragma unroll
  for (int mi = 0; mi < 4; ++mi)
#pragma unroll
  for (int ni = 0; ni < 2; ++ni) {
    int f  = bn*256 + nh*128 + wn*32 + ni*16 + l15;
    int m0 = bm*256 + mh*128 + wm*64 + mi*16 + l4*4;
    f32x4 v = acc[mh][nh][mi][ni];
    if (f < 1536) {
      short* dst = (f < 768) ? (Qb + f) : (Kb + (f - 768));
#pragma unroll
      for (int j = 0; j < 4; ++j)
        dst[(size_t)(m0 + j) * EMB] = f2bf(v[j]);
    } else {
      int f2 = f - 1536, bb2 = m0 >> 11, s = m0 & 2047;
      short4 pk = make_short4(f2bf(v[0]), f2bf(v[1]), f2bf(v[2]), f2bf(v[3]));
      *reinterpret_cast<short4*>(&Vt[((size_t)bb2 * EMB + f2) * SEQ + s]) = pk;
    }
  }
}

// ---------------------------------------------------------------------------
// energy: S[b,q,k] = (Q.K)*log2e/sqrt(768), fp16 (mask applied in softmax).
// Grid 512 = 8 b x 64 (supertiled 8qt x 8kt). Batch == XCD.
// ---------------------------------------------------------------------------
__global__ __launch_bounds__(512, 2) void energy(
    const short* __restrict__ Qb, const short* __restrict__ Kb,
    short* __restrict__ S)
{
  extern __shared__ char smem[];
  const int t = threadIdx.x, lane = t & 63, w = t >> 6;
  const int wm = w >> 2, wn = w & 3, l15 = lane & 15, l4 = lane >> 4;

  const int bid = blockIdx.x;
  const int nb = (bid & 7) * 64 + (bid >> 3);      // 512 % 8 == 0
  const int b = nb >> 6;                           // batch per XCD
  const int idx = nb & 63;
  const int sup = idx >> 2, sub = idx & 3;         // 2x2 supertiles
  const int qt = (sup >> 2) * 2 + (sub >> 1);
  const int kt = (sup & 3) * 2 + (sub & 1);

  const short* asrc = Qb + ((size_t)b*SEQ + qt*256) * EMB;
  const short* bsrc = Kb + ((size_t)b*SEQ + kt*256) * EMB;

  GEMM_PRO_BODY(asrc, bsrc, EMB, EMB, 12)

  const float SCL = 1.4426950408889634f / 27.712812921102035f;  // log2e/sqrt(768)
  short* srow = S + (size_t)b * SEQ * SEQ;
#pragma unroll
  for (int mh = 0; mh < 2; ++mh)
#pragma unroll
  for (int nh = 0; nh < 2; ++nh)
#pragma unroll
  for (int mi = 0; mi < 4; ++mi)
#pragma unroll
  for (int ni = 0; ni < 2; ++ni)
#pragma unroll
  for (int j = 0; j < 4; ++j) {
    int q = qt*256 + mh*128 + wm*64 + mi*16 + l4*4 + j;
    int k = kt*256 + nh*128 + wn*32 + ni*16 + l15;
    srow[(size_t)q*SEQ + k] = f2h(acc[mh][nh][mi][ni][j] * SCL);
  }
}

// ---------------------------------------------------------------------------
// softmax_rows: one wave per row; fp16 scores + int4 mask stream; bf16 P
// in place; invl = 1/sum. (unchanged, R3)
// ---------------------------------------------------------------------------
__global__ __launch_bounds__(256, 8) void softmax_rows(
    short* __restrict__ S, const int* __restrict__ mask,
    float* __restrict__ invl)
{
  const int w = threadIdx.x >> 6, lane = threadIdx.x & 63;
  const int r = blockIdx.x * 4 + w;
  short* row = S + (size_t)r * SEQ;
  const int4* mrow = reinterpret_cast<const int4*>(mask + (size_t)r * SEQ);

  float f[32];
#pragma unroll
  for (int c = 0; c < 4; ++c) {
    bf16x8 v = *reinterpret_cast<const bf16x8*>(&row[c*512 + lane*8]);
    int4 m0 = mrow[(c*512 + lane*8) >> 2];
    int4 m1 = mrow[((c*512 + lane*8) >> 2) + 1];
    f[c*8+0] = m0.x ? h2f(v[0]) : -30000.0f;
    f[c*8+1] = m0.y ? h2f(v[1]) : -30000.0f;
    f[c*8+2] = m0.z ? h2f(v[2]) : -30000.0f;
    f[c*8+3] = m0.w ? h2f(v[3]) : -30000.0f;
    f[c*8+4] = m1.x ? h2f(v[4]) : -30000.0f;
    f[c*8+5] = m1.y ? h2f(v[5]) : -30000.0f;
    f[c*8+6] = m1.z ? h2f(v[6]) : -30000.0f;
    f[c*8+7] = m1.w ? h2f(v[7]) : -30000.0f;
  }
  float m = -3.0e38f;
#pragma unroll
  for (int i = 0; i < 32; ++i) m = fmaxf(m, f[i]);
#pragma unroll
  for (int off = 32; off >= 1; off >>= 1) m = fmaxf(m, __shfl_xor(m, off));
  float sum = 0.f;
#pragma unroll
  for (int i = 0; i < 32; ++i) {
    f[i] = __builtin_amdgcn_exp2f(f[i] - m);
    sum += f[i];
  }
#pragma unroll
  for (int off = 32; off >= 1; off >>= 1) sum += __shfl_xor(sum, off);

#pragma unroll
  for (int c = 0; c < 4; ++c) {
    bf16x8 o;
#pragma unroll
    for (int j = 0; j < 8; ++j) o[j] = f2bf(f[c*8 + j]);
    *reinterpret_cast<bf16x8*>(&row[c*512 + lane*8]) = o;
  }
  if (lane == 0) invl[r] = 1.0f / sum;
}

// ---------------------------------------------------------------------------
// pv: out[b,q,d] = invl[b,q] * sum_k P[b,q,k]*Vt[b,d,k]. Grid 192 =
// 8 b x 8 qt x 3 dt (batch per XCD). K-tiles 32.
// ---------------------------------------------------------------------------
__global__ __launch_bounds__(512, 2) void pv(
    const short* __restrict__ P, const short* __restrict__ Vt,
    const float* __restrict__ invl, float* __restrict__ out)
{
  extern __shared__ char smem[];
  const int t = threadIdx.x, lane = t & 63, w = t >> 6;
  const int wm = w >> 2, wn = w & 3, l15 = lane & 15, l4 = lane >> 4;

  const int bid = blockIdx.x;
  const int nb = (bid & 7) * 24 + (bid >> 3);      // 192 % 8 == 0
  const int b = nb / 24;
  const int idx = nb % 24;
  const int qt = idx / 3, dt = idx % 3;

  const short* asrc = P  + ((size_t)b*SEQ + qt*256) * SEQ;
  const short* bsrc = Vt + ((size_t)b*EMB + dt*256) * SEQ;

  GEMM_PRO_BODY(asrc, bsrc, SEQ, SEQ, 32)

#pragma unroll
  for (int mh = 0; mh < 2; ++mh)
#pragma unroll
  for (int nh = 0; nh < 2; ++nh)
#pragma unroll
  for (int mi = 0; mi < 4; ++mi)
#pragma unroll
  for (int j = 0; j < 4; ++j) {
    int q = qt*256 + mh*128 + wm*64 + mi*16 + l4*4 + j;
    float il = invl[b*SEQ + q];
    float* orow = out + ((size_t)b*SEQ + q) * EMB;
#pragma unroll
    for (int ni = 0; ni < 2; ++ni) {
      int d = dt*256 + nh*128 + wn*32 + ni*16 + l15;
      orow[d] = acc[mh][nh][mi][ni][j] * il;
    }
  }
}

// ---------------------------------------------------------------------------
extern "C" void kernel_launch(void* const* d_in, const int* in_sizes, int n_in,
                              void* d_out, int out_size, void* d_ws, size_t ws_size,
                              hipStream_t stream)
{
  (void)in_sizes; (void)n_in; (void)out_size; (void)ws_size;
  const float* x  = (const float*)d_in[0];
  const float* Wv = (const float*)d_in[1];
  const float* Wk = (const float*)d_in[2];
  const float* Wq = (const float*)d_in[3];
  const int* mask = (const int*)d_in[4];
  float* out = (float*)d_out;

  // ws: Qb | Kb | Vt (bf16, 24MiB each) | S (fp16->bf16 in place, 64MiB) | invl
  // xb and Wb alias the S region (dead before energy writes S).
  short* Qb = (short*)d_ws;
  short* Kb = Qb + (size_t)M_TOT * EMB;
  short* Vt = Kb + (size_t)M_TOT * EMB;
  short* S  = Vt + (size_t)M_TOT * EMB;
  float* invl = (float*)(S + (size_t)NBATCH * SEQ * SEQ);
  short* xb = S;
  short* Wb = S + (size_t)M_TOT * EMB;

  cvt_all<<<dim3(2048), dim3(256), 0, stream>>>(x, Wq, Wk, Wv, xb, Wb);
  qkv_gemm<<<dim3(576), dim3(512), 131072, stream>>>(xb, Wb, Qb, Kb, Vt);
  energy<<<dim3(512), dim3(512), 131072, stream>>>(Qb, Kb, S);
  softmax_rows<<<dim3(4096), dim3(256), 0, stream>>>(S, mask, invl);
  pv<<<dim3(192), dim3(512), 131072, stream>>>(S, Vt, invl, out);
}